// Round 2
// baseline (696.472 us; speedup 1.0000x reference)
//
#include <hip/hip_runtime.h>
#include <math.h>

#define N_ROWS 131072
#define D 512
#define BLOCKS 4096
#define WAVES_PER_BLOCK 4
#define ROWS_PER_WAVE (N_ROWS / (BLOCKS * WAVES_PER_BLOCK))   // 8
#define R_PER_IT 4
#define N_IT (ROWS_PER_WAVE / R_PER_IT)                        // 2
#define ALPHA 50.0f
#define BETA 0.5f
#define EPS 1e-6f

// numerically stable softplus
__device__ __forceinline__ float softplusf(float x) {
    if (x > 0.0f) return x + log1pf(__expf(-x));
    return log1pf(__expf(x));
}

__global__ __launch_bounds__(256) void binloss_main(
    const float* __restrict__ o1, const float* __restrict__ o2,
    const int* __restrict__ target,
    float* __restrict__ sums /* [pos_sum, neg_sum] */,
    int* __restrict__ icnt /* [num_pos] */,
    unsigned int* __restrict__ done,
    float* __restrict__ out) {

    const int lane = threadIdx.x & 63;
    const int wave = threadIdx.x >> 6;           // 0..3
    const int gwave = blockIdx.x * WAVES_PER_BLOCK + wave;
    const int rowBase = gwave * ROWS_PER_WAVE;

    float posAcc = 0.0f, negAcc = 0.0f;
    int posCnt = 0;

    #pragma unroll
    for (int it = 0; it < N_IT; ++it) {
        const int row = rowBase + it * R_PER_IT;
        float dot[R_PER_IT], s1[R_PER_IT], s2[R_PER_IT];

        // 16 independent float4 loads issued together -> deep MLP
        #pragma unroll
        for (int r = 0; r < R_PER_IT; ++r) {
            const float4* p1 = (const float4*)(o1 + (size_t)(row + r) * D);
            const float4* p2 = (const float4*)(o2 + (size_t)(row + r) * D);
            float4 a0 = p1[lane];
            float4 a1 = p1[lane + 64];
            float4 b0 = p2[lane];
            float4 b1 = p2[lane + 64];
            dot[r] = a0.x * b0.x + a0.y * b0.y + a0.z * b0.z + a0.w * b0.w
                   + a1.x * b1.x + a1.y * b1.y + a1.z * b1.z + a1.w * b1.w;
            s1[r]  = a0.x * a0.x + a0.y * a0.y + a0.z * a0.z + a0.w * a0.w
                   + a1.x * a1.x + a1.y * a1.y + a1.z * a1.z + a1.w * a1.w;
            s2[r]  = b0.x * b0.x + b0.y * b0.y + b0.z * b0.z + b0.w * b0.w
                   + b1.x * b1.x + b1.y * b1.y + b1.z * b1.z + b1.w * b1.w;
        }

        // 12 independent butterfly chains -> ds_swizzle latency hidden by ILP
        #pragma unroll
        for (int off = 32; off > 0; off >>= 1) {
            #pragma unroll
            for (int r = 0; r < R_PER_IT; ++r) {
                dot[r] += __shfl_xor(dot[r], off);
                s1[r]  += __shfl_xor(s1[r], off);
                s2[r]  += __shfl_xor(s2[r], off);
            }
        }

        if (lane == 0) {
            #pragma unroll
            for (int r = 0; r < R_PER_IT; ++r) {
                float denom = fmaxf(sqrtf(s1[r]) * sqrtf(s2[r]), EPS);
                float d = dot[r] / denom;
                int t = target[row + r];
                if (t == 1) {
                    posAcc += (2.0f / BETA) * softplusf(-BETA * (d - 0.5f));
                    posCnt++;
                } else {
                    negAcc += (2.0f / ALPHA) * softplusf(ALPHA * (d - 2.0f));
                }
            }
        }
    }

    // block reduction: lane 0 of each of 4 waves -> LDS -> one atomic set per block
    __shared__ float sPos[WAVES_PER_BLOCK], sNeg[WAVES_PER_BLOCK];
    __shared__ int sCnt[WAVES_PER_BLOCK];
    if (lane == 0) {
        sPos[wave] = posAcc;
        sNeg[wave] = negAcc;
        sCnt[wave] = posCnt;
    }
    __syncthreads();
    if (threadIdx.x == 0) {
        float p = sPos[0] + sPos[1] + sPos[2] + sPos[3];
        float n = sNeg[0] + sNeg[1] + sNeg[2] + sNeg[3];
        int c = sCnt[0] + sCnt[1] + sCnt[2] + sCnt[3];
        atomicAdd(&sums[0], p);
        atomicAdd(&sums[1], n);
        atomicAdd(&icnt[0], c);
        __threadfence();
        unsigned int old = atomicAdd(done, 1u);
        if (old == (unsigned int)(gridDim.x - 1)) {
            // last block: all other blocks' sums are visible (their fence + our RMW)
            __threadfence();
            float ps = __hip_atomic_load(&sums[0], __ATOMIC_RELAXED, __HIP_MEMORY_SCOPE_AGENT);
            float ns = __hip_atomic_load(&sums[1], __ATOMIC_RELAXED, __HIP_MEMORY_SCOPE_AGENT);
            int np = __hip_atomic_load(&icnt[0], __ATOMIC_RELAXED, __HIP_MEMORY_SCOPE_AGENT);
            int nn = N_ROWS - np;
            float pos_loss = ps / (float)(np > 1 ? np : 1);
            float neg_loss = ns / (float)(nn > 1 ? nn : 1);
            out[0] = pos_loss + neg_loss;
        }
    }
}

extern "C" void kernel_launch(void* const* d_in, const int* in_sizes, int n_in,
                              void* d_out, int out_size, void* d_ws, size_t ws_size,
                              hipStream_t stream) {
    const float* o1 = (const float*)d_in[0];
    const float* o2 = (const float*)d_in[1];
    const int* tgt = (const int*)d_in[2];
    float* out = (float*)d_out;
    float* sums = (float*)d_ws;                       // 2 floats
    int* cnt = (int*)((char*)d_ws + 2 * sizeof(float));
    unsigned int* done = (unsigned int*)((char*)d_ws + 3 * sizeof(float));

    // zero accumulators + done flag (ws is re-poisoned to 0xAA before every launch)
    hipMemsetAsync(d_ws, 0, 16, stream);

    binloss_main<<<BLOCKS, 256, 0, stream>>>(o1, o2, tgt, sums, cnt, done, out);
}